// Round 10
// baseline (182.211 us; speedup 1.0000x reference)
//
#include <hip/hip_runtime.h>
#include <hip/hip_bf16.h>

#define H 128
#define O 64
#define RELS 4

typedef short short8 __attribute__((ext_vector_type(8)));
typedef float f32x4 __attribute__((ext_vector_type(4)));
typedef unsigned int u32x4 __attribute__((ext_vector_type(4)));

static __device__ __forceinline__ unsigned short f2b(float x) {
    __hip_bfloat16 h = __float2bfloat16(x);           // RNE
    return *reinterpret_cast<unsigned short*>(&h);
}
static __device__ __forceinline__ float blo(unsigned u) { return __uint_as_float(u << 16); }
static __device__ __forceinline__ float bhi(unsigned u) { return __uint_as_float(u & 0xffff0000u); }

// NOTE: parameter names must not collide with vector member names (.x/.y/.z/.w)
#define ACC8(acc, uv, wt)                                           \
    acc[0] += (wt) * blo(uv.x); acc[1] += (wt) * bhi(uv.x);         \
    acc[2] += (wt) * blo(uv.y); acc[3] += (wt) * bhi(uv.y);         \
    acc[4] += (wt) * blo(uv.z); acc[5] += (wt) * bhi(uv.z);         \
    acc[6] += (wt) * blo(uv.w); acc[7] += (wt) * bhi(uv.w);

// ---------- fused prep: hist FIRST (overlaps cvt), embed->bf16 (nt loads), W->WT ----------
__global__ void k_prep(const float* __restrict__ embed, unsigned short* __restrict__ eb,
                       const float* __restrict__ W, unsigned short* __restrict__ WT,
                       const int* __restrict__ dst, int* __restrict__ cnt,
                       int n4, int wtot, int E, int RE, int N, int b_h, int b_cvt) {
    int b = blockIdx.x;
    if (b < b_h) {
        int i = b * 256 + threadIdx.x;
        if (i < RE) { int r = i / E; atomicAdd(&cnt[r * N + dst[i]], 1); }
    } else if (b < b_h + b_cvt) {
        int base = (b - b_h) * 1024;
#pragma unroll
        for (int k = 0; k < 4; ++k) {
            int i = base + k * 256 + threadIdx.x;
            if (i < n4) {
                f32x4 v = __builtin_nontemporal_load(((const f32x4*)embed) + i);
                ushort4 o;
                o.x = f2b(v[0]); o.y = f2b(v[1]); o.z = f2b(v[2]); o.w = f2b(v[3]);
                ((ushort4*)eb)[i] = o;
            }
        }
    } else {
        int i = (b - b_h - b_cvt) * 256 + threadIdx.x;
        if (i < wtot) {
            int r = i >> 13;            // O*H = 8192
            int n = (i >> 7) & (O - 1);
            int k = i & (H - 1);
            WT[i] = f2b(W[((size_t)r * H + k) * O + n]);
        }
    }
}

// ---------- scan1 with fused per-node total (totdeg = sum_r cnt[r*N+i]) ----------
__global__ void k_scan1(const int* __restrict__ cnt, int* __restrict__ offs,
                        int* __restrict__ bsum, int n, int N_) {
    __shared__ int sh[256];
    int t = threadIdx.x;
    int base = blockIdx.x * 1024 + t * 4;
    int4 v = make_int4(0, 0, 0, 0);
    if (base + 3 < n && (N_ & 3) == 0) {
#pragma unroll
        for (int r = 0; r < RELS; ++r) {
            int4 c = *(const int4*)(cnt + (size_t)r * N_ + base);
            v.x += c.x; v.y += c.y; v.z += c.z; v.w += c.w;
        }
    } else {
        for (int j = 0; j < 4; ++j) {
            int i = base + j;
            if (i < n) {
                int s = 0;
                for (int r = 0; r < RELS; ++r) s += cnt[(size_t)r * N_ + i];
                (&v.x)[j] = s;
            }
        }
    }
    int s = v.x + v.y + v.z + v.w;
    sh[t] = s; __syncthreads();
    for (int off = 1; off < 256; off <<= 1) {
        int x = (t >= off) ? sh[t - off] : 0;
        __syncthreads();
        sh[t] += x;
        __syncthreads();
    }
    int incl = sh[t];
    int ex = incl - s;
    if (base < n)     offs[base]     = ex;
    if (base + 1 < n) offs[base + 1] = ex + v.x;
    if (base + 2 < n) offs[base + 2] = ex + v.x + v.y;
    if (base + 3 < n) offs[base + 3] = ex + v.x + v.y + v.z;
    if (t == 255) bsum[blockIdx.x] = incl;
}

__global__ void k_scan2(int* __restrict__ bsum, int nb) {
    __shared__ int sh[512];
    int t = threadIdx.x;
    int s = (t < nb) ? bsum[t] : 0;
    sh[t] = s; __syncthreads();
    for (int off = 1; off < 512; off <<= 1) {
        int x = (t >= off) ? sh[t - off] : 0;
        __syncthreads();
        sh[t] += x;
        __syncthreads();
    }
    if (t < nb) bsum[t] = sh[t] - s;
}

// finalize offs + build per-(rel,node) cursors
__global__ void k_scan3c(int* __restrict__ offs, const int* __restrict__ bsum,
                         const int* __restrict__ cnt, int* __restrict__ cursor,
                         int n, int total, int N_) {
    int i = blockIdx.x * blockDim.x + threadIdx.x;
    if (i < n) {
        int off = offs[i] + bsum[i >> 10];
        offs[i] = off;
        int c0 = cnt[i], c1 = cnt[N_ + i], c2 = cnt[2 * N_ + i];
        cursor[i]          = off;
        cursor[N_ + i]     = off + c0;
        cursor[2 * N_ + i] = off + c0 + c1;
        cursor[3 * N_ + i] = off + c0 + c1 + c2;
    }
    if (i == 0) offs[n] = total;
}

// per edge: record {rowidx = r*N+src, w = 1/deg_r(dst)} at CSR position
__global__ void k_fill(const int* __restrict__ src, const int* __restrict__ dst,
                       const int* __restrict__ cnt, int* __restrict__ cursor,
                       uint2* __restrict__ ue, int E, int RE, int N) {
    int i = blockIdx.x * blockDim.x + threadIdx.x;
    if (i >= RE) return;
    int r = i / E;
    int d = dst[i];
    int pos = atomicAdd(&cursor[r * N + d], 1);
    float w = 1.0f / (float)max(cnt[r * N + d], 1);
    ue[pos] = make_uint2((unsigned)(r * N + src[i]), __float_as_uint(w));
}

// ---------- FUSED Layer1-pull + Layer2-GEMM ----------
// Block = 16 nodes. Phase 1: pull (16 lanes/node, uint4 gathers, unroll 4) into
// LDS tile. Barrier. Phase 2: wave wv MFMAs the tile vs W[wv], writes T[wv]
// with NON-TEMPORAL stores (streamed, never L2-reused).
__global__ __launch_bounds__(256) void k_l1g(const unsigned short* __restrict__ eb,
                                             const int* __restrict__ offs2,
                                             const uint2* __restrict__ ue,
                                             const float* __restrict__ bias1,
                                             const unsigned short* __restrict__ WT,
                                             unsigned short* __restrict__ T, int N) {
    __shared__ __align__(16) unsigned short hs[16][136];
    __shared__ __align__(16) unsigned short st[4][16][72];
    int tid = threadIdx.x, wv = tid >> 6, l = tid & 63;
    int row0 = blockIdx.x * 16;
    int nloc = tid >> 4;               // 0..15
    int node = row0 + nloc;
    int q = l & 15;

    // ---- phase 1: pull ----
    float a[8] = {0.f, 0.f, 0.f, 0.f, 0.f, 0.f, 0.f, 0.f};
    float c[8] = {0.f, 0.f, 0.f, 0.f, 0.f, 0.f, 0.f, 0.f};
    if (node < N) {
        int beg = offs2[node], end = offs2[node + 1];
        unsigned N1 = (unsigned)N, N2 = (unsigned)(2 * N);
        int e = beg;
        for (; e + 4 <= end; e += 4) {
            uint2 p0 = ue[e], p1 = ue[e + 1], p2 = ue[e + 2], p3 = ue[e + 3];
            unsigned s0 = p0.x; if (s0 >= N2) s0 -= N2; if (s0 >= N1) s0 -= N1;
            unsigned s1 = p1.x; if (s1 >= N2) s1 -= N2; if (s1 >= N1) s1 -= N1;
            unsigned s2 = p2.x; if (s2 >= N2) s2 -= N2; if (s2 >= N1) s2 -= N1;
            unsigned s3 = p3.x; if (s3 >= N2) s3 -= N2; if (s3 >= N1) s3 -= N1;
            float w0 = __uint_as_float(p0.y), w1 = __uint_as_float(p1.y);
            float w2 = __uint_as_float(p2.y), w3 = __uint_as_float(p3.y);
            uint4 u0 = *(const uint4*)(eb + (size_t)s0 * H + q * 8);
            uint4 u1 = *(const uint4*)(eb + (size_t)s1 * H + q * 8);
            uint4 u2 = *(const uint4*)(eb + (size_t)s2 * H + q * 8);
            uint4 u3 = *(const uint4*)(eb + (size_t)s3 * H + q * 8);
            ACC8(a, u0, w0);
            ACC8(c, u1, w1);
            ACC8(a, u2, w2);
            ACC8(c, u3, w3);
        }
        for (; e + 2 <= end; e += 2) {
            uint2 p0 = ue[e], p1 = ue[e + 1];
            unsigned s0 = p0.x; if (s0 >= N2) s0 -= N2; if (s0 >= N1) s0 -= N1;
            unsigned s1 = p1.x; if (s1 >= N2) s1 -= N2; if (s1 >= N1) s1 -= N1;
            float w0 = __uint_as_float(p0.y), w1 = __uint_as_float(p1.y);
            uint4 u0 = *(const uint4*)(eb + (size_t)s0 * H + q * 8);
            uint4 u1 = *(const uint4*)(eb + (size_t)s1 * H + q * 8);
            ACC8(a, u0, w0);
            ACC8(c, u1, w1);
        }
        if (e < end) {
            uint2 p0 = ue[e];
            unsigned s0 = p0.x; if (s0 >= N2) s0 -= N2; if (s0 >= N1) s0 -= N1;
            float w0 = __uint_as_float(p0.y);
            uint4 u0 = *(const uint4*)(eb + (size_t)s0 * H + q * 8);
            ACC8(a, u0, w0);
        }
        float4 b0 = *(const float4*)(bias1 + q * 8);
        float4 b1 = *(const float4*)(bias1 + q * 8 + 4);
        float f0 = fmaxf(a[0] + c[0] + b0.x, 0.f);
        float f1 = fmaxf(a[1] + c[1] + b0.y, 0.f);
        float f2 = fmaxf(a[2] + c[2] + b0.z, 0.f);
        float f3 = fmaxf(a[3] + c[3] + b0.w, 0.f);
        float f4 = fmaxf(a[4] + c[4] + b1.x, 0.f);
        float f5 = fmaxf(a[5] + c[5] + b1.y, 0.f);
        float f6 = fmaxf(a[6] + c[6] + b1.z, 0.f);
        float f7 = fmaxf(a[7] + c[7] + b1.w, 0.f);
        uint4 o;
        o.x = (unsigned)f2b(f0) | ((unsigned)f2b(f1) << 16);
        o.y = (unsigned)f2b(f2) | ((unsigned)f2b(f3) << 16);
        o.z = (unsigned)f2b(f4) | ((unsigned)f2b(f5) << 16);
        o.w = (unsigned)f2b(f6) | ((unsigned)f2b(f7) << 16);
        *(uint4*)&hs[nloc][q * 8] = o;
    } else {
        uint4 zz = make_uint4(0, 0, 0, 0);
        *(uint4*)&hs[nloc][q * 8] = zz;
    }
    __syncthreads();

    // ---- phase 2: GEMM, wave wv owns relation wv ----
    int rA = l & 15, kb = (l >> 4) * 8;
    short8 af[4];
#pragma unroll
    for (int kk = 0; kk < 4; ++kk)
        af[kk] = *(const short8*)&hs[rA][kk * 32 + kb];

    const unsigned short* Wb = WT + (size_t)wv * O * H;
    f32x4 z = {0.f, 0.f, 0.f, 0.f};
    f32x4 acc[4] = {z, z, z, z};
#pragma unroll
    for (int nt = 0; nt < 4; ++nt) {
        short8 bf[4];
#pragma unroll
        for (int kk = 0; kk < 4; ++kk)
            bf[kk] = *(const short8*)(Wb + ((size_t)(nt * 16 + rA)) * H + kk * 32 + kb);
#pragma unroll
        for (int kk = 0; kk < 4; ++kk)
            acc[nt] = __builtin_amdgcn_mfma_f32_16x16x32_bf16(af[kk], bf[kk], acc[nt], 0, 0, 0);
    }

    // C layout: col = rA, row = (l>>4)*4 + j  -> wave-private LDS transpose -> T (nt stores)
#pragma unroll
    for (int nt = 0; nt < 4; ++nt)
#pragma unroll
        for (int j = 0; j < 4; ++j)
            st[wv][(l >> 4) * 4 + j][nt * 16 + rA] = f2b(acc[nt][j]);

#pragma unroll
    for (int i = 0; i < 2; ++i) {
        int rr = i * 8 + (l >> 3);
        u32x4 v = *(const u32x4*)&st[wv][rr][(l & 7) * 8];
        int grow = row0 + rr;
        if (grow < N)
            __builtin_nontemporal_store(v, (u32x4*)(T + ((size_t)wv * N + grow) * O + (l & 7) * 8));
    }
}

// ---------- Layer 2: 8 lanes per node (8 nodes/wave), uint4 gathers, unroll 4 ----------
__global__ void k_pull2(const unsigned short* __restrict__ T, const int* __restrict__ offs2,
                        const uint2* __restrict__ ue, const float* __restrict__ bias2,
                        float* __restrict__ out, int N) {
    int node = blockIdx.x * 32 + (threadIdx.x >> 3);
    if (node >= N) return;
    int o = threadIdx.x & 7;
    int beg = offs2[node], end = offs2[node + 1];

    float a[8] = {0.f, 0.f, 0.f, 0.f, 0.f, 0.f, 0.f, 0.f};
    float c[8] = {0.f, 0.f, 0.f, 0.f, 0.f, 0.f, 0.f, 0.f};

    int e = beg;
    for (; e + 4 <= end; e += 4) {
        uint2 p0 = ue[e], p1 = ue[e + 1], p2 = ue[e + 2], p3 = ue[e + 3];
        float w0 = __uint_as_float(p0.y), w1 = __uint_as_float(p1.y);
        float w2 = __uint_as_float(p2.y), w3 = __uint_as_float(p3.y);
        uint4 u0 = *(const uint4*)(T + (size_t)p0.x * O + o * 8);
        uint4 u1 = *(const uint4*)(T + (size_t)p1.x * O + o * 8);
        uint4 u2 = *(const uint4*)(T + (size_t)p2.x * O + o * 8);
        uint4 u3 = *(const uint4*)(T + (size_t)p3.x * O + o * 8);
        ACC8(a, u0, w0);
        ACC8(c, u1, w1);
        ACC8(a, u2, w2);
        ACC8(c, u3, w3);
    }
    for (; e + 2 <= end; e += 2) {
        uint2 p0 = ue[e], p1 = ue[e + 1];
        float w0 = __uint_as_float(p0.y), w1 = __uint_as_float(p1.y);
        uint4 u0 = *(const uint4*)(T + (size_t)p0.x * O + o * 8);
        uint4 u1 = *(const uint4*)(T + (size_t)p1.x * O + o * 8);
        ACC8(a, u0, w0);
        ACC8(c, u1, w1);
    }
    if (e < end) {
        uint2 p0 = ue[e];
        float w0 = __uint_as_float(p0.y);
        uint4 u0 = *(const uint4*)(T + (size_t)p0.x * O + o * 8);
        ACC8(a, u0, w0);
    }

    float4 b0 = *(const float4*)(bias2 + o * 8);
    float4 b1 = *(const float4*)(bias2 + o * 8 + 4);
    f32x4 v0, v1;
    v0[0] = a[0] + c[0] + b0.x; v0[1] = a[1] + c[1] + b0.y;
    v0[2] = a[2] + c[2] + b0.z; v0[3] = a[3] + c[3] + b0.w;
    v1[0] = a[4] + c[4] + b1.x; v1[1] = a[5] + c[5] + b1.y;
    v1[2] = a[6] + c[6] + b1.z; v1[3] = a[7] + c[7] + b1.w;
    __builtin_nontemporal_store(v0, (f32x4*)(out + (size_t)node * O + o * 8));
    __builtin_nontemporal_store(v1, (f32x4*)(out + (size_t)node * O + o * 8 + 4));
}

extern "C" void kernel_launch(void* const* d_in, const int* in_sizes, int n_in,
                              void* d_out, int out_size, void* d_ws, size_t ws_size,
                              hipStream_t stream) {
    const float* embed  = (const float*)d_in[0];
    const float* weight = (const float*)d_in[1];
    const float* bias1  = (const float*)d_in[2];
    const float* bias2  = (const float*)d_in[3];
    const int*   esrc   = (const int*)d_in[4];
    const int*   edst   = (const int*)d_in[5];
    float* out = (float*)d_out;

    const int N = in_sizes[0] / H;
    const int E = in_sizes[4] / RELS;
    const int RN = RELS * N;
    const int RE = RELS * E;

    char* p = (char*)d_ws;
    auto alloc = [&](size_t bytes) {
        char* q = p;
        p += (bytes + 255) & ~(size_t)255;
        return q;
    };
    int* cnt    = (int*)alloc((size_t)RN * 4);
    int* offs2  = (int*)alloc(((size_t)N + 1) * 4);
    int* cursor = (int*)alloc((size_t)RN * 4);
    int* bsum   = (int*)alloc(4096);
    uint2* ue   = (uint2*)alloc((size_t)RE * 8);
    unsigned short* eb  = (unsigned short*)alloc((size_t)N * H * 2);
    unsigned short* WT  = (unsigned short*)alloc((size_t)RELS * O * H * 2);
    unsigned short* T   = (unsigned short*)alloc((size_t)RELS * N * O * 2);

    hipMemsetAsync(cnt, 0, (size_t)RN * 4, stream);

    int n4 = N * H / 4;
    int wtot = RELS * O * H;
    int b_h   = (RE + 255) / 256;
    int b_cvt = (n4 + 1023) / 1024;
    int b_w   = (wtot + 255) / 256;
    k_prep<<<b_h + b_cvt + b_w, 256, 0, stream>>>(embed, eb, weight, WT, edst, cnt,
                                                  n4, wtot, E, RE, N, b_h, b_cvt);

    int nb = (N + 1023) / 1024;
    k_scan1<<<nb, 256, 0, stream>>>(cnt, offs2, bsum, N, N);
    k_scan2<<<1, 512, 0, stream>>>(bsum, nb);
    k_scan3c<<<(N + 255) / 256, 256, 0, stream>>>(offs2, bsum, cnt, cursor, N, RE, N);

    k_fill<<<(RE + 255) / 256, 256, 0, stream>>>(esrc, edst, cnt, cursor, ue, E, RE, N);

    k_l1g<<<(N + 15) / 16, 256, 0, stream>>>(eb, offs2, ue, bias1, WT, T, N);

    k_pull2<<<(N + 31) / 32, 256, 0, stream>>>(T, offs2, ue, bias2, out, N);
}

// Round 11
// 170.488 us; speedup vs baseline: 1.0688x; 1.0688x over previous
//
#include <hip/hip_runtime.h>
#include <hip/hip_bf16.h>

#define H 128
#define O 64
#define RELS 4

typedef short short8 __attribute__((ext_vector_type(8)));
typedef float f32x4 __attribute__((ext_vector_type(4)));
typedef unsigned int u32x4 __attribute__((ext_vector_type(4)));

static __device__ __forceinline__ unsigned short f2b(float x) {
    __hip_bfloat16 h = __float2bfloat16(x);           // RNE
    return *reinterpret_cast<unsigned short*>(&h);
}
static __device__ __forceinline__ float blo(unsigned u) { return __uint_as_float(u << 16); }
static __device__ __forceinline__ float bhi(unsigned u) { return __uint_as_float(u & 0xffff0000u); }

// NOTE: parameter names must not collide with vector member names (.x/.y/.z/.w)
#define ACC8(acc, uv, wt)                                           \
    acc[0] += (wt) * blo(uv.x); acc[1] += (wt) * bhi(uv.x);         \
    acc[2] += (wt) * blo(uv.y); acc[3] += (wt) * bhi(uv.y);         \
    acc[4] += (wt) * blo(uv.z); acc[5] += (wt) * bhi(uv.z);         \
    acc[6] += (wt) * blo(uv.w); acc[7] += (wt) * bhi(uv.w);

// ---------- persistent prep: hist, embed->bf16, W->WT (grid-stride over virtual blocks) ----------
__global__ void k_prep(const float* __restrict__ embed, unsigned short* __restrict__ eb,
                       const float* __restrict__ W, unsigned short* __restrict__ WT,
                       const int* __restrict__ dst, int* __restrict__ cnt,
                       int n4, int wtot, int E, int RE, int N, int b_h, int b_cvt, int b_tot) {
    for (int b = blockIdx.x; b < b_tot; b += gridDim.x) {
        if (b < b_h) {
            int i = b * 256 + threadIdx.x;
            if (i < RE) { int r = i / E; atomicAdd(&cnt[r * N + dst[i]], 1); }
        } else if (b < b_h + b_cvt) {
            int base = (b - b_h) * 1024;
#pragma unroll
            for (int k = 0; k < 4; ++k) {
                int i = base + k * 256 + threadIdx.x;
                if (i < n4) {
                    f32x4 v = __builtin_nontemporal_load(((const f32x4*)embed) + i);
                    ushort4 o;
                    o.x = f2b(v[0]); o.y = f2b(v[1]); o.z = f2b(v[2]); o.w = f2b(v[3]);
                    ((ushort4*)eb)[i] = o;
                }
            }
        } else {
            int i = (b - b_h - b_cvt) * 256 + threadIdx.x;
            if (i < wtot) {
                int r = i >> 13;            // O*H = 8192
                int n = (i >> 7) & (O - 1);
                int k = i & (H - 1);
                WT[i] = f2b(W[((size_t)r * H + k) * O + n]);
            }
        }
    }
}

// ---------- scan1 with fused per-node total (totdeg = sum_r cnt[r*N+i]) ----------
__global__ void k_scan1(const int* __restrict__ cnt, int* __restrict__ offs,
                        int* __restrict__ bsum, int n, int N_) {
    __shared__ int sh[256];
    int t = threadIdx.x;
    int base = blockIdx.x * 1024 + t * 4;
    int4 v = make_int4(0, 0, 0, 0);
    if (base + 3 < n && (N_ & 3) == 0) {
#pragma unroll
        for (int r = 0; r < RELS; ++r) {
            int4 c = *(const int4*)(cnt + (size_t)r * N_ + base);
            v.x += c.x; v.y += c.y; v.z += c.z; v.w += c.w;
        }
    } else {
        for (int j = 0; j < 4; ++j) {
            int i = base + j;
            if (i < n) {
                int s = 0;
                for (int r = 0; r < RELS; ++r) s += cnt[(size_t)r * N_ + i];
                (&v.x)[j] = s;
            }
        }
    }
    int s = v.x + v.y + v.z + v.w;
    sh[t] = s; __syncthreads();
    for (int off = 1; off < 256; off <<= 1) {
        int x = (t >= off) ? sh[t - off] : 0;
        __syncthreads();
        sh[t] += x;
        __syncthreads();
    }
    int incl = sh[t];
    int ex = incl - s;
    if (base < n)     offs[base]     = ex;
    if (base + 1 < n) offs[base + 1] = ex + v.x;
    if (base + 2 < n) offs[base + 2] = ex + v.x + v.y;
    if (base + 3 < n) offs[base + 3] = ex + v.x + v.y + v.z;
    if (t == 255) bsum[blockIdx.x] = incl;
}

__global__ void k_scan2(int* __restrict__ bsum, int nb) {
    __shared__ int sh[512];
    int t = threadIdx.x;
    int s = (t < nb) ? bsum[t] : 0;
    sh[t] = s; __syncthreads();
    for (int off = 1; off < 512; off <<= 1) {
        int x = (t >= off) ? sh[t - off] : 0;
        __syncthreads();
        sh[t] += x;
        __syncthreads();
    }
    if (t < nb) bsum[t] = sh[t] - s;
}

// finalize offs + build per-(rel,node) cursors
__global__ void k_scan3c(int* __restrict__ offs, const int* __restrict__ bsum,
                         const int* __restrict__ cnt, int* __restrict__ cursor,
                         int n, int total, int N_) {
    int i = blockIdx.x * blockDim.x + threadIdx.x;
    if (i < n) {
        int off = offs[i] + bsum[i >> 10];
        offs[i] = off;
        int c0 = cnt[i], c1 = cnt[N_ + i], c2 = cnt[2 * N_ + i];
        cursor[i]          = off;
        cursor[N_ + i]     = off + c0;
        cursor[2 * N_ + i] = off + c0 + c1;
        cursor[3 * N_ + i] = off + c0 + c1 + c2;
    }
    if (i == 0) offs[n] = total;
}

// per edge: record {rowidx = r*N+src, w = 1/deg_r(dst)} at CSR position (grid-stride)
__global__ void k_fill(const int* __restrict__ src, const int* __restrict__ dst,
                       const int* __restrict__ cnt, int* __restrict__ cursor,
                       uint2* __restrict__ ue, int E, int RE, int N) {
    for (int i = blockIdx.x * blockDim.x + threadIdx.x; i < RE; i += gridDim.x * blockDim.x) {
        int r = i / E;
        int d = dst[i];
        int pos = atomicAdd(&cursor[r * N + d], 1);
        float w = 1.0f / (float)max(cnt[r * N + d], 1);
        ue[pos] = make_uint2((unsigned)(r * N + src[i]), __float_as_uint(w));
    }
}

// ---------- PERSISTENT fused Layer1-pull + Layer2-GEMM ----------
// Grid-stride over 16-node tiles. Double-buffered LDS h-tile: one barrier per
// tile; pull(k+1) overlaps other waves' gemm(k). B-fragments (wave wv = relation
// wv) hoisted into registers ONCE — zero WT reloads in the loop.
__global__ __launch_bounds__(256) void k_l1g(const unsigned short* __restrict__ eb,
                                             const int* __restrict__ offs2,
                                             const uint2* __restrict__ ue,
                                             const float* __restrict__ bias1,
                                             const unsigned short* __restrict__ WT,
                                             unsigned short* __restrict__ T,
                                             int N, int ntiles) {
    __shared__ __align__(16) unsigned short hs[2][16][136];
    __shared__ __align__(16) unsigned short st[4][16][72];
    int tid = threadIdx.x, wv = tid >> 6, l = tid & 63;
    int nloc = tid >> 4;               // 0..15
    int q = l & 15;
    int rA = l & 15, kb = (l >> 4) * 8;
    unsigned N1 = (unsigned)N, N2 = (unsigned)(2 * N);

    // hoist: bias (for pull) and B-fragments (for gemm)
    float4 b0 = *(const float4*)(bias1 + q * 8);
    float4 b1 = *(const float4*)(bias1 + q * 8 + 4);
    const unsigned short* Wb = WT + (size_t)wv * O * H;
    short8 bf[4][4];
#pragma unroll
    for (int nt = 0; nt < 4; ++nt)
#pragma unroll
        for (int kk = 0; kk < 4; ++kk)
            bf[nt][kk] = *(const short8*)(Wb + ((size_t)(nt * 16 + rA)) * H + kk * 32 + kb);

    int buf = 0;
    for (int tile = blockIdx.x; tile < ntiles; tile += gridDim.x, buf ^= 1) {
        int row0 = tile * 16;
        int node = row0 + nloc;

        // ---- phase 1: pull into hs[buf] ----
        float a[8] = {0.f, 0.f, 0.f, 0.f, 0.f, 0.f, 0.f, 0.f};
        float c[8] = {0.f, 0.f, 0.f, 0.f, 0.f, 0.f, 0.f, 0.f};
        if (node < N) {
            int2 be = *(const int2*)(offs2 + node);   // beg, end in one 8B load
            int beg = be.x, end = be.y;
            int e = beg;
            for (; e + 4 <= end; e += 4) {
                uint2 p0 = ue[e], p1 = ue[e + 1], p2 = ue[e + 2], p3 = ue[e + 3];
                unsigned s0 = p0.x; if (s0 >= N2) s0 -= N2; if (s0 >= N1) s0 -= N1;
                unsigned s1 = p1.x; if (s1 >= N2) s1 -= N2; if (s1 >= N1) s1 -= N1;
                unsigned s2 = p2.x; if (s2 >= N2) s2 -= N2; if (s2 >= N1) s2 -= N1;
                unsigned s3 = p3.x; if (s3 >= N2) s3 -= N2; if (s3 >= N1) s3 -= N1;
                float w0 = __uint_as_float(p0.y), w1 = __uint_as_float(p1.y);
                float w2 = __uint_as_float(p2.y), w3 = __uint_as_float(p3.y);
                uint4 u0 = *(const uint4*)(eb + (size_t)s0 * H + q * 8);
                uint4 u1 = *(const uint4*)(eb + (size_t)s1 * H + q * 8);
                uint4 u2 = *(const uint4*)(eb + (size_t)s2 * H + q * 8);
                uint4 u3 = *(const uint4*)(eb + (size_t)s3 * H + q * 8);
                ACC8(a, u0, w0);
                ACC8(c, u1, w1);
                ACC8(a, u2, w2);
                ACC8(c, u3, w3);
            }
            for (; e + 2 <= end; e += 2) {
                uint2 p0 = ue[e], p1 = ue[e + 1];
                unsigned s0 = p0.x; if (s0 >= N2) s0 -= N2; if (s0 >= N1) s0 -= N1;
                unsigned s1 = p1.x; if (s1 >= N2) s1 -= N2; if (s1 >= N1) s1 -= N1;
                float w0 = __uint_as_float(p0.y), w1 = __uint_as_float(p1.y);
                uint4 u0 = *(const uint4*)(eb + (size_t)s0 * H + q * 8);
                uint4 u1 = *(const uint4*)(eb + (size_t)s1 * H + q * 8);
                ACC8(a, u0, w0);
                ACC8(c, u1, w1);
            }
            if (e < end) {
                uint2 p0 = ue[e];
                unsigned s0 = p0.x; if (s0 >= N2) s0 -= N2; if (s0 >= N1) s0 -= N1;
                float w0 = __uint_as_float(p0.y);
                uint4 u0 = *(const uint4*)(eb + (size_t)s0 * H + q * 8);
                ACC8(a, u0, w0);
            }
            float f0 = fmaxf(a[0] + c[0] + b0.x, 0.f);
            float f1 = fmaxf(a[1] + c[1] + b0.y, 0.f);
            float f2 = fmaxf(a[2] + c[2] + b0.z, 0.f);
            float f3 = fmaxf(a[3] + c[3] + b0.w, 0.f);
            float f4 = fmaxf(a[4] + c[4] + b1.x, 0.f);
            float f5 = fmaxf(a[5] + c[5] + b1.y, 0.f);
            float f6 = fmaxf(a[6] + c[6] + b1.z, 0.f);
            float f7 = fmaxf(a[7] + c[7] + b1.w, 0.f);
            uint4 o;
            o.x = (unsigned)f2b(f0) | ((unsigned)f2b(f1) << 16);
            o.y = (unsigned)f2b(f2) | ((unsigned)f2b(f3) << 16);
            o.z = (unsigned)f2b(f4) | ((unsigned)f2b(f5) << 16);
            o.w = (unsigned)f2b(f6) | ((unsigned)f2b(f7) << 16);
            *(uint4*)&hs[buf][nloc][q * 8] = o;
        } else {
            uint4 zz = make_uint4(0, 0, 0, 0);
            *(uint4*)&hs[buf][nloc][q * 8] = zz;
        }
        __syncthreads();

        // ---- phase 2: gemm, wave wv owns relation wv ----
        short8 af[4];
#pragma unroll
        for (int kk = 0; kk < 4; ++kk)
            af[kk] = *(const short8*)&hs[buf][rA][kk * 32 + kb];

        f32x4 z = {0.f, 0.f, 0.f, 0.f};
        f32x4 acc[4] = {z, z, z, z};
#pragma unroll
        for (int nt = 0; nt < 4; ++nt)
#pragma unroll
            for (int kk = 0; kk < 4; ++kk)
                acc[nt] = __builtin_amdgcn_mfma_f32_16x16x32_bf16(af[kk], bf[nt][kk], acc[nt], 0, 0, 0);

        // C layout: col = rA, row = (l>>4)*4 + j  -> wave-private LDS transpose -> T
#pragma unroll
        for (int nt = 0; nt < 4; ++nt)
#pragma unroll
            for (int j = 0; j < 4; ++j)
                st[wv][(l >> 4) * 4 + j][nt * 16 + rA] = f2b(acc[nt][j]);

#pragma unroll
        for (int i = 0; i < 2; ++i) {
            int rr = i * 8 + (l >> 3);
            u32x4 v = *(const u32x4*)&st[wv][rr][(l & 7) * 8];
            int grow = row0 + rr;
            if (grow < N)
                __builtin_nontemporal_store(v, (u32x4*)(T + ((size_t)wv * N + grow) * O + (l & 7) * 8));
        }
    }
}

// ---------- Layer 2: persistent, 8 lanes per node (8 nodes/wave), unroll 4 ----------
__global__ void k_pull2(const unsigned short* __restrict__ T, const int* __restrict__ offs2,
                        const uint2* __restrict__ ue, const float* __restrict__ bias2,
                        float* __restrict__ out, int N, int ngroups) {
    int o = threadIdx.x & 7;
    float4 b0 = *(const float4*)(bias2 + o * 8);
    float4 b1 = *(const float4*)(bias2 + o * 8 + 4);

    for (int g = blockIdx.x; g < ngroups; g += gridDim.x) {
        int node = g * 32 + (threadIdx.x >> 3);
        if (node >= N) continue;
        int2 be = *(const int2*)(offs2 + node);
        int beg = be.x, end = be.y;

        float a[8] = {0.f, 0.f, 0.f, 0.f, 0.f, 0.f, 0.f, 0.f};
        float c[8] = {0.f, 0.f, 0.f, 0.f, 0.f, 0.f, 0.f, 0.f};

        int e = beg;
        for (; e + 4 <= end; e += 4) {
            uint2 p0 = ue[e], p1 = ue[e + 1], p2 = ue[e + 2], p3 = ue[e + 3];
            float w0 = __uint_as_float(p0.y), w1 = __uint_as_float(p1.y);
            float w2 = __uint_as_float(p2.y), w3 = __uint_as_float(p3.y);
            uint4 u0 = *(const uint4*)(T + (size_t)p0.x * O + o * 8);
            uint4 u1 = *(const uint4*)(T + (size_t)p1.x * O + o * 8);
            uint4 u2 = *(const uint4*)(T + (size_t)p2.x * O + o * 8);
            uint4 u3 = *(const uint4*)(T + (size_t)p3.x * O + o * 8);
            ACC8(a, u0, w0);
            ACC8(c, u1, w1);
            ACC8(a, u2, w2);
            ACC8(c, u3, w3);
        }
        for (; e + 2 <= end; e += 2) {
            uint2 p0 = ue[e], p1 = ue[e + 1];
            float w0 = __uint_as_float(p0.y), w1 = __uint_as_float(p1.y);
            uint4 u0 = *(const uint4*)(T + (size_t)p0.x * O + o * 8);
            uint4 u1 = *(const uint4*)(T + (size_t)p1.x * O + o * 8);
            ACC8(a, u0, w0);
            ACC8(c, u1, w1);
        }
        if (e < end) {
            uint2 p0 = ue[e];
            float w0 = __uint_as_float(p0.y);
            uint4 u0 = *(const uint4*)(T + (size_t)p0.x * O + o * 8);
            ACC8(a, u0, w0);
        }

        f32x4 v0, v1;
        v0[0] = a[0] + c[0] + b0.x; v0[1] = a[1] + c[1] + b0.y;
        v0[2] = a[2] + c[2] + b0.z; v0[3] = a[3] + c[3] + b0.w;
        v1[0] = a[4] + c[4] + b1.x; v1[1] = a[5] + c[5] + b1.y;
        v1[2] = a[6] + c[6] + b1.z; v1[3] = a[7] + c[7] + b1.w;
        __builtin_nontemporal_store(v0, (f32x4*)(out + (size_t)node * O + o * 8));
        __builtin_nontemporal_store(v1, (f32x4*)(out + (size_t)node * O + o * 8 + 4));
    }
}

extern "C" void kernel_launch(void* const* d_in, const int* in_sizes, int n_in,
                              void* d_out, int out_size, void* d_ws, size_t ws_size,
                              hipStream_t stream) {
    const float* embed  = (const float*)d_in[0];
    const float* weight = (const float*)d_in[1];
    const float* bias1  = (const float*)d_in[2];
    const float* bias2  = (const float*)d_in[3];
    const int*   esrc   = (const int*)d_in[4];
    const int*   edst   = (const int*)d_in[5];
    float* out = (float*)d_out;

    const int N = in_sizes[0] / H;
    const int E = in_sizes[4] / RELS;
    const int RN = RELS * N;
    const int RE = RELS * E;

    char* p = (char*)d_ws;
    auto alloc = [&](size_t bytes) {
        char* q = p;
        p += (bytes + 255) & ~(size_t)255;
        return q;
    };
    int* cnt    = (int*)alloc((size_t)RN * 4);
    int* offs2  = (int*)alloc(((size_t)N + 1) * 4);
    int* cursor = (int*)alloc((size_t)RN * 4);
    int* bsum   = (int*)alloc(4096);
    uint2* ue   = (uint2*)alloc((size_t)RE * 8);
    unsigned short* eb  = (unsigned short*)alloc((size_t)N * H * 2);
    unsigned short* WT  = (unsigned short*)alloc((size_t)RELS * O * H * 2);
    unsigned short* T   = (unsigned short*)alloc((size_t)RELS * N * O * 2);

    hipMemsetAsync(cnt, 0, (size_t)RN * 4, stream);

    int n4 = N * H / 4;
    int wtot = RELS * O * H;
    int b_h   = (RE + 255) / 256;
    int b_cvt = (n4 + 1023) / 1024;
    int b_w   = (wtot + 255) / 256;
    int b_tot = b_h + b_cvt + b_w;
    int gprep = b_tot < 2048 ? b_tot : 2048;
    k_prep<<<gprep, 256, 0, stream>>>(embed, eb, weight, WT, edst, cnt,
                                      n4, wtot, E, RE, N, b_h, b_cvt, b_tot);

    int nb = (N + 1023) / 1024;
    k_scan1<<<nb, 256, 0, stream>>>(cnt, offs2, bsum, N, N);
    k_scan2<<<1, 512, 0, stream>>>(bsum, nb);
    k_scan3c<<<(N + 255) / 256, 256, 0, stream>>>(offs2, bsum, cnt, cursor, N, RE, N);

    int bfill = (RE + 255) / 256;
    k_fill<<<(bfill < 2048 ? bfill : 2048), 256, 0, stream>>>(esrc, edst, cnt, cursor, ue, E, RE, N);

    int ntiles = (N + 15) / 16;
    k_l1g<<<(ntiles < 2048 ? ntiles : 2048), 256, 0, stream>>>(eb, offs2, ue, bias1, WT, T, N, ntiles);

    int ngroups = (N + 31) / 32;
    k_pull2<<<(ngroups < 2048 ? ngroups : 2048), 256, 0, stream>>>(T, offs2, ue, bias2, out, N, ngroups);
}